// Round 21
// baseline (207.275 us; speedup 1.0000x reference)
//
#include <hip/hip_runtime.h>
#include <hip/hip_fp16.h>
#include <math.h>

#define BKT_SHIFT 8
#define BKT_NODES 256
#define HB 16

// ---- pass 1: per-bucket histogram (int4-vectorized dst read) ----
__global__ __launch_bounds__(256) void k_hist(const int* __restrict__ dst,
                                              int* __restrict__ bcnt, int E, int NB) {
    __shared__ int lh[512];
    for (int i = threadIdx.x; i < NB; i += 256) lh[i] = 0;
    __syncthreads();
    int base = blockIdx.x * 4096;
    if (base + 4096 <= E) {
        const int4* d4 = (const int4*)(dst + base);
#pragma unroll
        for (int k = 0; k < 4; ++k) {
            int4 v = d4[k * 256 + threadIdx.x];
            atomicAdd(&lh[v.x >> BKT_SHIFT], 1);
            atomicAdd(&lh[v.y >> BKT_SHIFT], 1);
            atomicAdd(&lh[v.z >> BKT_SHIFT], 1);
            atomicAdd(&lh[v.w >> BKT_SHIFT], 1);
        }
    } else {
        for (int k = 0; k < 16; ++k) {
            int i = base + k * 256 + threadIdx.x;
            if (i < E) atomicAdd(&lh[dst[i] >> BKT_SHIFT], 1);
        }
    }
    __syncthreads();
    for (int i = threadIdx.x; i < NB; i += 256)
        if (lh[i]) atomicAdd(&bcnt[i], lh[i]);
}

// ---- exclusive scan over NB buckets (single block) ----
__global__ __launch_bounds__(512) void k_bscan(const int* __restrict__ bc,
                                               int* __restrict__ boff,
                                               int* __restrict__ bcur, int NB, int E) {
    __shared__ int s[512];
    __shared__ int carry;
    if (threadIdx.x == 0) carry = 0;
    __syncthreads();
    for (int base = 0; base < NB; base += 512) {
        int i = base + threadIdx.x;
        int v = (i < NB) ? bc[i] : 0;
        s[threadIdx.x] = v;
        __syncthreads();
        for (int off = 1; off < 512; off <<= 1) {
            int t = (threadIdx.x >= off) ? s[threadIdx.x - off] : 0;
            __syncthreads();
            s[threadIdx.x] += t;
            __syncthreads();
        }
        if (i < NB) {
            int ex = carry + s[threadIdx.x] - v;
            boff[i] = ex;
            bcur[i] = ex;
        }
        __syncthreads();
        if (threadIdx.x == 0) carry += s[511];
        __syncthreads();
    }
    if (threadIdx.x == 0) boff[NB] = E;
}

// ---- pass 2: partition edges; record = (d&255)<<24 | src ----
__global__ __launch_bounds__(1024) void k_part(const int* __restrict__ src,
                                               const int* __restrict__ dst,
                                               int* __restrict__ bcur,
                                               int* __restrict__ ebuf, int E, int NB) {
    __shared__ int lh[512];
    for (int i = threadIdx.x; i < NB; i += 1024) lh[i] = 0;
    __syncthreads();
    int base = blockIdx.x * 8192;
    if (base + 8192 <= E) {
        const int4* d4 = (const int4*)(dst + base);
#pragma unroll
        for (int k = 0; k < 2; ++k) {
            int4 v = d4[k * 1024 + threadIdx.x];
            atomicAdd(&lh[v.x >> BKT_SHIFT], 1);
            atomicAdd(&lh[v.y >> BKT_SHIFT], 1);
            atomicAdd(&lh[v.z >> BKT_SHIFT], 1);
            atomicAdd(&lh[v.w >> BKT_SHIFT], 1);
        }
    } else {
        for (int k = 0; k < 8; ++k) {
            int i = base + k * 1024 + threadIdx.x;
            if (i < E) atomicAdd(&lh[dst[i] >> BKT_SHIFT], 1);
        }
    }
    __syncthreads();
    for (int t = threadIdx.x; t < NB; t += 1024) {
        int c = lh[t];
        lh[t] = c ? atomicAdd(&bcur[t], c) : 0;
    }
    __syncthreads();
    if (base + 8192 <= E) {
        const int4* d4 = (const int4*)(dst + base);
        const int4* s4 = (const int4*)(src + base);
#pragma unroll
        for (int k = 0; k < 2; ++k) {
            int4 dv = d4[k * 1024 + threadIdx.x];
            int4 sv = s4[k * 1024 + threadIdx.x];
            int p;
            p = atomicAdd(&lh[dv.x >> BKT_SHIFT], 1); ebuf[p] = ((dv.x & 255) << 24) | sv.x;
            p = atomicAdd(&lh[dv.y >> BKT_SHIFT], 1); ebuf[p] = ((dv.y & 255) << 24) | sv.y;
            p = atomicAdd(&lh[dv.z >> BKT_SHIFT], 1); ebuf[p] = ((dv.z & 255) << 24) | sv.z;
            p = atomicAdd(&lh[dv.w >> BKT_SHIFT], 1); ebuf[p] = ((dv.w & 255) << 24) | sv.w;
        }
    } else {
        for (int k = 0; k < 8; ++k) {
            int i = base + k * 1024 + threadIdx.x;
            if (i < E) {
                int d = dst[i];
                int p = atomicAdd(&lh[d >> BKT_SHIFT], 1);
                ebuf[p] = ((d & 255) << 24) | src[i];
            }
        }
    }
}

// ---- pass 3: counting sort + dinv + hx (fused) ----
__global__ __launch_bounds__(256) void k_lsort(const int* __restrict__ boff,
                                               const int* __restrict__ ebuf,
                                               const float* __restrict__ x,
                                               int* __restrict__ rowstart,
                                               float* __restrict__ dinv,
                                               __half2* __restrict__ hx,
                                               int* __restrict__ csr, int n, int NB) {
    __shared__ int off[256];
    __shared__ int cnt[256];
    int b = blockIdx.x;
    int start = boff[b], end = boff[b + 1];
    cnt[threadIdx.x] = 0;
    __syncthreads();
    for (int i = start + threadIdx.x; i < end; i += 256)
        atomicAdd(&cnt[((unsigned)ebuf[i]) >> 24], 1);
    __syncthreads();
    int v = cnt[threadIdx.x];
    off[threadIdx.x] = v;
    __syncthreads();
    for (int o = 1; o < 256; o <<= 1) {
        int t = (threadIdx.x >= o) ? off[threadIdx.x - o] : 0;
        __syncthreads();
        off[threadIdx.x] += t;
        __syncthreads();
    }
    int excl = off[threadIdx.x] - v;
    int node = (b << BKT_SHIFT) + threadIdx.x;
    if (node < n) {
        rowstart[node] = start + excl;
        float dv = rsqrtf((float)v + 1.0f);  // +1 = self-loop
        dinv[node] = dv;
        const float4* xp = (const float4*)(x + (size_t)node * 8);
        float4 a = xp[0], c = xp[1];
        __half2* hp = hx + (size_t)node * 4;
        hp[0] = __floats2half2_rn(a.x * dv, a.y * dv);
        hp[1] = __floats2half2_rn(a.z * dv, a.w * dv);
        hp[2] = __floats2half2_rn(c.x * dv, c.y * dv);
        hp[3] = __floats2half2_rn(c.z * dv, c.w * dv);
    }
    __syncthreads();
    off[threadIdx.x] = excl;  // reuse as cursor
    __syncthreads();
    for (int i = start + threadIdx.x; i < end; i += 256) {
        int rec = ebuf[i];
        int d = ((unsigned)rec) >> 24;
        int pos = atomicAdd(&off[d], 1);
        csr[start + pos] = rec & 0xFFFFFF;
    }
    if (b == NB - 1 && threadIdx.x == 0) rowstart[n] = end;
}

// ---- fused layer-1 + gemm2 (unchanged r20 champion) ----
__global__ __launch_bounds__(256) void k_agg1g(const int* __restrict__ rs, const int* __restrict__ csr,
                                               const float* __restrict__ dinv, const __half2* __restrict__ hx,
                                               const float* __restrict__ W1, const float* __restrict__ bias,
                                               const float* __restrict__ W2, __half* __restrict__ hw2, int n) {
    __shared__ float w[512];        // W1 [8][64]
    __shared__ float sb[64];
    __shared__ float w2s[64 * 36];  // W2 [64][32] padded to stride 36
    for (int i = threadIdx.x; i < 512; i += 256) w[i] = W1[i];
    if (threadIdx.x < 64) sb[threadIdx.x] = bias[threadIdx.x];
    for (int i = threadIdx.x; i < 2048; i += 256) {
        int r = i >> 5, c = i & 31;
        w2s[r * 36 + c] = W2[i];
    }
    __syncthreads();
    int wid = (blockIdx.x * 256 + threadIdx.x) >> 2;   // node
    if (wid >= n) return;
    int jp = threadIdx.x & 3;
    int start = rs[wid], end = rs[wid + 1];
    float ax = 0.f, ay = 0.f;
    for (int i = start; i < end; i += 16) {
        int idx[16];
        float msk[16];
#pragma unroll
        for (int k = 0; k < 16; ++k) {
            int ii = i + k;
            bool ok = ii < end;
            idx[k] = ok ? csr[ii] : wid;
            msk[k] = ok ? 1.f : 0.f;
        }
        float2 f[16];
#pragma unroll
        for (int k = 0; k < 16; ++k)
            f[k] = __half22float2(hx[((size_t)idx[k] << 2) + jp]);
#pragma unroll
        for (int k = 0; k < 16; ++k) {
            ax = fmaf(msk[k], f[k].x, ax);
            ay = fmaf(msk[k], f[k].y, ay);
        }
    }
    {
        float2 f = __half22float2(hx[((size_t)wid << 2) + jp]);
        ax += f.x; ay += f.y;
    }
    float bx = __shfl_xor(ax, 1), by = __shfl_xor(ay, 1);
    float cx = __shfl_xor(ax, 2), cy = __shfl_xor(ay, 2);
    float dx = __shfl_xor(bx, 2), dy = __shfl_xor(by, 2);
    float dv = dinv[wid];
    int fb = jp * 16;
    const float* r0 = &w[(2 * jp) * 64 + fb];          const float* r1 = r0 + 64;
    const float* r2 = &w[(2 * (jp ^ 1)) * 64 + fb];    const float* r3 = r2 + 64;
    const float* r4 = &w[(2 * (jp ^ 2)) * 64 + fb];    const float* r5 = r4 + 64;
    const float* r6 = &w[(2 * (jp ^ 3)) * 64 + fb];    const float* r7 = r6 + 64;
    const float* sbp = &sb[fb];
    float4 o4[4];
#pragma unroll
    for (int m4 = 0; m4 < 4; ++m4) {
        float4 wa = *(const float4*)&r0[m4 * 4];
        float4 wb = *(const float4*)&r1[m4 * 4];
        float4 wc = *(const float4*)&r2[m4 * 4];
        float4 wd = *(const float4*)&r3[m4 * 4];
        float4 we = *(const float4*)&r4[m4 * 4];
        float4 wf = *(const float4*)&r5[m4 * 4];
        float4 wg = *(const float4*)&r6[m4 * 4];
        float4 wh = *(const float4*)&r7[m4 * 4];
        float4 o;
        o.x = dv * (ax * wa.x + ay * wb.x + bx * wc.x + by * wd.x + cx * we.x + cy * wf.x + dx * wg.x + dy * wh.x) + sbp[m4 * 4 + 0];
        o.y = dv * (ax * wa.y + ay * wb.y + bx * wc.y + by * wd.y + cx * we.y + cy * wf.y + dx * wg.y + dy * wh.y) + sbp[m4 * 4 + 1];
        o.z = dv * (ax * wa.z + ay * wb.z + bx * wc.z + by * wd.z + cx * we.z + cy * wf.z + dx * wg.z + dy * wh.z) + sbp[m4 * 4 + 2];
        o.w = dv * (ax * wa.w + ay * wb.w + bx * wc.w + by * wd.w + cx * we.w + cy * wf.w + dx * wg.w + dy * wh.w) + sbp[m4 * 4 + 3];
        o.x = o.x > 0.f ? o.x : expm1f(o.x);
        o.y = o.y > 0.f ? o.y : expm1f(o.y);
        o.z = o.z > 0.f ? o.z : expm1f(o.z);
        o.w = o.w > 0.f ? o.w : expm1f(o.w);
        o4[m4] = o;
    }
    float4 acc[8];
#pragma unroll
    for (int j4 = 0; j4 < 8; ++j4) acc[j4] = make_float4(0.f, 0.f, 0.f, 0.f);
#pragma unroll
    for (int m4 = 0; m4 < 4; ++m4) {
        int mm = (m4 + jp) & 3;
        float4 ov;
        {
            float4 t0 = (mm & 2) ? o4[2] : o4[0];
            float4 t1 = (mm & 2) ? o4[3] : o4[1];
            ov = (mm & 1) ? t1 : t0;
        }
#pragma unroll
        for (int q = 0; q < 4; ++q) {
            float om = q == 0 ? ov.x : q == 1 ? ov.y : q == 2 ? ov.z : ov.w;
            const float4* wr = (const float4*)&w2s[(fb + mm * 4 + q) * 36];
#pragma unroll
            for (int j4 = 0; j4 < 8; ++j4) {
                float4 wv = wr[j4];
                acc[j4].x = fmaf(om, wv.x, acc[j4].x);
                acc[j4].y = fmaf(om, wv.y, acc[j4].y);
                acc[j4].z = fmaf(om, wv.z, acc[j4].z);
                acc[j4].w = fmaf(om, wv.w, acc[j4].w);
            }
        }
    }
    bool hi1 = (jp & 1) != 0;
    float4 keep1[4];
#pragma unroll
    for (int i = 0; i < 4; ++i) {
        float4 lo = acc[i], hi = acc[i + 4];
        float4 mine, send;
        mine.x = hi1 ? hi.x : lo.x;  send.x = hi1 ? lo.x : hi.x;
        mine.y = hi1 ? hi.y : lo.y;  send.y = hi1 ? lo.y : hi.y;
        mine.z = hi1 ? hi.z : lo.z;  send.z = hi1 ? lo.z : hi.z;
        mine.w = hi1 ? hi.w : lo.w;  send.w = hi1 ? lo.w : hi.w;
        mine.x += __shfl_xor(send.x, 1);
        mine.y += __shfl_xor(send.y, 1);
        mine.z += __shfl_xor(send.z, 1);
        mine.w += __shfl_xor(send.w, 1);
        keep1[i] = mine;
    }
    bool hi2 = (jp & 2) != 0;
    float4 fin[2];
#pragma unroll
    for (int i = 0; i < 2; ++i) {
        float4 lo = keep1[i], hi = keep1[i + 2];
        float4 mine, send;
        mine.x = hi2 ? hi.x : lo.x;  send.x = hi2 ? lo.x : hi.x;
        mine.y = hi2 ? hi.y : lo.y;  send.y = hi2 ? lo.y : hi.y;
        mine.z = hi2 ? hi.z : lo.z;  send.z = hi2 ? lo.z : hi.z;
        mine.w = hi2 ? hi.w : lo.w;  send.w = hi2 ? lo.w : hi.w;
        mine.x += __shfl_xor(send.x, 2);
        mine.y += __shfl_xor(send.y, 2);
        mine.z += __shfl_xor(send.z, 2);
        mine.w += __shfl_xor(send.w, 2);
        fin[i] = mine;
    }
    int jb = (jp & 1) * 16 + (jp & 2) * 4;
    __half2 h01 = __floats2half2_rn(fin[0].x * dv, fin[0].y * dv);
    __half2 h23 = __floats2half2_rn(fin[0].z * dv, fin[0].w * dv);
    __half2 h45 = __floats2half2_rn(fin[1].x * dv, fin[1].y * dv);
    __half2 h67 = __floats2half2_rn(fin[1].z * dv, fin[1].w * dv);
    uint4 u;
    u.x = *(unsigned*)&h01; u.y = *(unsigned*)&h23;
    u.z = *(unsigned*)&h45; u.w = *(unsigned*)&h67;
    *(uint4*)((char*)hw2 + (size_t)wid * 64 + jb * 2) = u;
}

// ---- fused layer-2 agg + head: 18 nodes/block (16 + 2 halo), g2 in LDS only ----
__global__ __launch_bounds__(320) void k_agg2h(const int* __restrict__ rs, const int* __restrict__ csr,
                                               const float* __restrict__ dinv, const __half* __restrict__ hw,
                                               const float* __restrict__ bias,
                                               const float* __restrict__ cw, const float* __restrict__ cb,
                                               const float* __restrict__ fw, const float* __restrict__ fb,
                                               float* __restrict__ out, int n, int nrows) {
    __shared__ float tile[18 * 36];   // g2 rows (stride 36)
    __shared__ float scwT[96 * 16];   // conv W [(ci*3+k)*16 + co]
    __shared__ float ytile[16 * 20];
    __shared__ float sfwT[22 * 16];
    __shared__ float scb[16], sfb[22], sbb[32];
    for (int i = threadIdx.x; i < 1536; i += 320) {
        int co = i / 96, rem = i - co * 96;
        scwT[rem * 16 + co] = cw[i];
    }
    for (int i = threadIdx.x; i < 352; i += 320) {
        int co = i / 22, col = i - co * 22;
        sfwT[col * 16 + co] = fw[i];
    }
    if (threadIdx.x < 16) scb[threadIdx.x] = cb[threadIdx.x];
    if (threadIdx.x < 22) sfb[threadIdx.x] = fb[threadIdx.x];
    if (threadIdx.x < 32) sbb[threadIdx.x] = bias[threadIdx.x];
    __syncthreads();
    int base = blockIdx.x * HB;
    int slot = threadIdx.x >> 4;     // 0..19
    int j = threadIdx.x & 15;
    int wid = base + slot;
    if (slot < 18 && wid < n) {
        int start = rs[wid], end = rs[wid + 1];
        const __half2* hp = (const __half2*)hw;
        float ax = 0.f, ay = 0.f;
        for (int i = start; i < end; i += 16) {
            int idx[16];
            float msk[16];
#pragma unroll
            for (int k = 0; k < 16; ++k) {
                int ii = i + k;
                bool ok = ii < end;
                idx[k] = ok ? csr[ii] : wid;
                msk[k] = ok ? 1.f : 0.f;
            }
            float2 f[16];
#pragma unroll
            for (int k = 0; k < 16; ++k)
                f[k] = __half22float2(hp[((size_t)idx[k] << 4) + j]);
#pragma unroll
            for (int k = 0; k < 16; ++k) {
                ax = fmaf(msk[k], f[k].x, ax);
                ay = fmaf(msk[k], f[k].y, ay);
            }
        }
        float dv = dinv[wid];
        float2 fs = __half22float2(hp[((size_t)wid << 4) + j]);
        float vx = dv * (ax + fs.x) + sbb[2 * j];
        float vy = dv * (ay + fs.y) + sbb[2 * j + 1];
        vx = vx > 0.f ? vx : expm1f(vx);
        vy = vy > 0.f ? vy : expm1f(vy);
        tile[slot * 36 + 2 * j]     = vx;
        tile[slot * 36 + 2 * j + 1] = vy;
    }
    __syncthreads();
    int rcnt = nrows - base; if (rcnt > HB) rcnt = HB;
    if (threadIdx.x < 256) {
        int r = threadIdx.x >> 4, co = threadIdx.x & 15;
        if (r < rcnt) {
            float acc = scb[co];
#pragma unroll
            for (int k = 0; k < 3; ++k) {
                const float* tr = &tile[(r + k) * 36];
#pragma unroll
                for (int ci = 0; ci < 32; ++ci)
                    acc = fmaf(tr[ci], scwT[(ci * 3 + k) * 16 + co], acc);
            }
            ytile[r * 20 + co] = acc > 0.f ? acc : 0.f;
        }
    }
    __syncthreads();
    int items = rcnt * 22;
    for (int it = threadIdx.x; it < items; it += 320) {
        int row = it / 22, col = it - row * 22;
        const float* yr = &ytile[row * 20];
        const float* wc = &sfwT[col * 16];
        float s = sfb[col];
#pragma unroll
        for (int co4 = 0; co4 < 4; ++co4) {
            float4 yv = *(const float4*)&yr[co4 * 4];
            float4 wv = *(const float4*)&wc[co4 * 4];
            s += yv.x * wv.x + yv.y * wv.y + yv.z * wv.z + yv.w * wv.w;
        }
        out[(size_t)base * 22 + it] = s;
    }
}

extern "C" void kernel_launch(void* const* d_in, const int* in_sizes, int n_in,
                              void* d_out, int out_size, void* d_ws, size_t ws_size,
                              hipStream_t stream) {
    const float* x  = (const float*)d_in[0];
    const int*   ei = (const int*)d_in[1];   // int32 (JAX x64 disabled)
    const float* W1 = (const float*)d_in[2];
    const float* b1 = (const float*)d_in[3];
    const float* W2 = (const float*)d_in[4];
    const float* b2 = (const float*)d_in[5];
    const float* cw = (const float*)d_in[6];
    const float* cb = (const float*)d_in[7];
    const float* fw = (const float*)d_in[8];
    const float* fb = (const float*)d_in[9];
    float* out = (float*)d_out;

    int N = in_sizes[0] / 8;       // 100000
    int E = in_sizes[1] / 2;       // 3200000
    const int* src = ei;
    const int* dst = ei + E;
    int NB = (N + BKT_NODES - 1) >> BKT_SHIFT;  // 391

    auto alignB = [](size_t v) { return (v + 1023) & ~(size_t)1023; };
    char* wsb = (char*)d_ws;
    size_t o = 0;
    int* bcnt = (int*)(wsb + o);      o += 2048;
    int* boff = (int*)(wsb + o);      o += 2048;
    int* bcur = (int*)(wsb + o);      o += 2048;
    int* rowstart = (int*)(wsb + o);  o += alignB((size_t)(N + 1) * 4);
    float* dinv = (float*)(wsb + o);  o += alignB((size_t)N * 4);
    int* csr = (int*)(wsb + o);       o += alignB((size_t)E * 4 + 256);
    __half2* hx = (__half2*)(wsb + o);  o += alignB((size_t)N * 8 * 2);   // [N][8] fp16
    __half* hw2 = (__half*)(wsb + o);   o += alignB((size_t)N * 32 * 2);  // [N][32] fp16
    int* ebuf = (int*)(wsb + o);      o += alignB((size_t)E * 4);         // partition scratch

    hipMemsetAsync(bcnt, 0, (size_t)NB * sizeof(int), stream);
    k_hist<<<(E + 4095) / 4096, 256, 0, stream>>>(dst, bcnt, E, NB);
    k_bscan<<<1, 512, 0, stream>>>(bcnt, boff, bcur, NB, E);
    k_part<<<(E + 8191) / 8192, 1024, 0, stream>>>(src, dst, bcur, ebuf, E, NB);
    k_lsort<<<NB, 256, 0, stream>>>(boff, ebuf, x, rowstart, dinv, hx, csr, N, NB);

    k_agg1g<<<(int)(((size_t)N * 4 + 255) / 256), 256, 0, stream>>>(rowstart, csr, dinv, hx, W1, b1, W2, hw2, N);

    int nrows = N - 2;
    k_agg2h<<<(nrows + HB - 1) / HB, 320, 0, stream>>>(rowstart, csr, dinv, hw2, b2,
                                                       cw, cb, fw, fb, out, N, nrows);
}

// Round 22
// 172.062 us; speedup vs baseline: 1.2047x; 1.2047x over previous
//
#include <hip/hip_runtime.h>
#include <hip/hip_fp16.h>
#include <math.h>

#define BKT_SHIFT 8
#define BKT_NODES 256
#define HROWS 64

// ---- pass 1: per-bucket histogram (int4-vectorized dst read) ----
__global__ __launch_bounds__(256) void k_hist(const int* __restrict__ dst,
                                              int* __restrict__ bcnt, int E, int NB) {
    __shared__ int lh[512];
    for (int i = threadIdx.x; i < NB; i += 256) lh[i] = 0;
    __syncthreads();
    int base = blockIdx.x * 4096;
    if (base + 4096 <= E) {
        const int4* d4 = (const int4*)(dst + base);
#pragma unroll
        for (int k = 0; k < 4; ++k) {
            int4 v = d4[k * 256 + threadIdx.x];
            atomicAdd(&lh[v.x >> BKT_SHIFT], 1);
            atomicAdd(&lh[v.y >> BKT_SHIFT], 1);
            atomicAdd(&lh[v.z >> BKT_SHIFT], 1);
            atomicAdd(&lh[v.w >> BKT_SHIFT], 1);
        }
    } else {
        for (int k = 0; k < 16; ++k) {
            int i = base + k * 256 + threadIdx.x;
            if (i < E) atomicAdd(&lh[dst[i] >> BKT_SHIFT], 1);
        }
    }
    __syncthreads();
    for (int i = threadIdx.x; i < NB; i += 256)
        if (lh[i]) atomicAdd(&bcnt[i], lh[i]);
}

// ---- exclusive scan over NB buckets (single block) ----
__global__ __launch_bounds__(512) void k_bscan(const int* __restrict__ bc,
                                               int* __restrict__ boff,
                                               int* __restrict__ bcur, int NB, int E) {
    __shared__ int s[512];
    __shared__ int carry;
    if (threadIdx.x == 0) carry = 0;
    __syncthreads();
    for (int base = 0; base < NB; base += 512) {
        int i = base + threadIdx.x;
        int v = (i < NB) ? bc[i] : 0;
        s[threadIdx.x] = v;
        __syncthreads();
        for (int off = 1; off < 512; off <<= 1) {
            int t = (threadIdx.x >= off) ? s[threadIdx.x - off] : 0;
            __syncthreads();
            s[threadIdx.x] += t;
            __syncthreads();
        }
        if (i < NB) {
            int ex = carry + s[threadIdx.x] - v;
            boff[i] = ex;
            bcur[i] = ex;
        }
        __syncthreads();
        if (threadIdx.x == 0) carry += s[511];
        __syncthreads();
    }
    if (threadIdx.x == 0) boff[NB] = E;
}

// ---- pass 2: partition edges; record = (d&255)<<24 | src ----
__global__ __launch_bounds__(1024) void k_part(const int* __restrict__ src,
                                               const int* __restrict__ dst,
                                               int* __restrict__ bcur,
                                               int* __restrict__ ebuf, int E, int NB) {
    __shared__ int lh[512];
    for (int i = threadIdx.x; i < NB; i += 1024) lh[i] = 0;
    __syncthreads();
    int base = blockIdx.x * 8192;
    if (base + 8192 <= E) {
        const int4* d4 = (const int4*)(dst + base);
#pragma unroll
        for (int k = 0; k < 2; ++k) {
            int4 v = d4[k * 1024 + threadIdx.x];
            atomicAdd(&lh[v.x >> BKT_SHIFT], 1);
            atomicAdd(&lh[v.y >> BKT_SHIFT], 1);
            atomicAdd(&lh[v.z >> BKT_SHIFT], 1);
            atomicAdd(&lh[v.w >> BKT_SHIFT], 1);
        }
    } else {
        for (int k = 0; k < 8; ++k) {
            int i = base + k * 1024 + threadIdx.x;
            if (i < E) atomicAdd(&lh[dst[i] >> BKT_SHIFT], 1);
        }
    }
    __syncthreads();
    for (int t = threadIdx.x; t < NB; t += 1024) {
        int c = lh[t];
        lh[t] = c ? atomicAdd(&bcur[t], c) : 0;
    }
    __syncthreads();
    if (base + 8192 <= E) {
        const int4* d4 = (const int4*)(dst + base);
        const int4* s4 = (const int4*)(src + base);
#pragma unroll
        for (int k = 0; k < 2; ++k) {
            int4 dv = d4[k * 1024 + threadIdx.x];
            int4 sv = s4[k * 1024 + threadIdx.x];
            int p;
            p = atomicAdd(&lh[dv.x >> BKT_SHIFT], 1); ebuf[p] = ((dv.x & 255) << 24) | sv.x;
            p = atomicAdd(&lh[dv.y >> BKT_SHIFT], 1); ebuf[p] = ((dv.y & 255) << 24) | sv.y;
            p = atomicAdd(&lh[dv.z >> BKT_SHIFT], 1); ebuf[p] = ((dv.z & 255) << 24) | sv.z;
            p = atomicAdd(&lh[dv.w >> BKT_SHIFT], 1); ebuf[p] = ((dv.w & 255) << 24) | sv.w;
        }
    } else {
        for (int k = 0; k < 8; ++k) {
            int i = base + k * 1024 + threadIdx.x;
            if (i < E) {
                int d = dst[i];
                int p = atomicAdd(&lh[d >> BKT_SHIFT], 1);
                ebuf[p] = ((d & 255) << 24) | src[i];
            }
        }
    }
}

// ---- pass 3: counting sort + dinv + hx (fused) ----
__global__ __launch_bounds__(256) void k_lsort(const int* __restrict__ boff,
                                               const int* __restrict__ ebuf,
                                               const float* __restrict__ x,
                                               int* __restrict__ rowstart,
                                               float* __restrict__ dinv,
                                               __half2* __restrict__ hx,
                                               int* __restrict__ csr, int n, int NB) {
    __shared__ int off[256];
    __shared__ int cnt[256];
    int b = blockIdx.x;
    int start = boff[b], end = boff[b + 1];
    cnt[threadIdx.x] = 0;
    __syncthreads();
    for (int i = start + threadIdx.x; i < end; i += 256)
        atomicAdd(&cnt[((unsigned)ebuf[i]) >> 24], 1);
    __syncthreads();
    int v = cnt[threadIdx.x];
    off[threadIdx.x] = v;
    __syncthreads();
    for (int o = 1; o < 256; o <<= 1) {
        int t = (threadIdx.x >= o) ? off[threadIdx.x - o] : 0;
        __syncthreads();
        off[threadIdx.x] += t;
        __syncthreads();
    }
    int excl = off[threadIdx.x] - v;
    int node = (b << BKT_SHIFT) + threadIdx.x;
    if (node < n) {
        rowstart[node] = start + excl;
        float dv = rsqrtf((float)v + 1.0f);  // +1 = self-loop
        dinv[node] = dv;
        const float4* xp = (const float4*)(x + (size_t)node * 8);
        float4 a = xp[0], c = xp[1];
        __half2* hp = hx + (size_t)node * 4;
        hp[0] = __floats2half2_rn(a.x * dv, a.y * dv);
        hp[1] = __floats2half2_rn(a.z * dv, a.w * dv);
        hp[2] = __floats2half2_rn(c.x * dv, c.y * dv);
        hp[3] = __floats2half2_rn(c.z * dv, c.w * dv);
    }
    __syncthreads();
    off[threadIdx.x] = excl;  // reuse as cursor
    __syncthreads();
    for (int i = start + threadIdx.x; i < end; i += 256) {
        int rec = ebuf[i];
        int d = ((unsigned)rec) >> 24;
        int pos = atomicAdd(&off[d], 1);
        csr[start + pos] = rec & 0xFFFFFF;
    }
    if (b == NB - 1 && threadIdx.x == 0) rowstart[n] = end;
}

// ---- fused layer-1 + gemm2: 16 nodes/wave, 4 lanes/node, 16-deep gather,
//      quad-allgather -> g1 (in regs) -> @W2 (k-rotated, conflict-free) -> butterfly -> hw2 ----
__global__ __launch_bounds__(256) void k_agg1g(const int* __restrict__ rs, const int* __restrict__ csr,
                                               const float* __restrict__ dinv, const __half2* __restrict__ hx,
                                               const float* __restrict__ W1, const float* __restrict__ bias,
                                               const float* __restrict__ W2, __half* __restrict__ hw2, int n) {
    __shared__ float w[512];        // W1 [8][64]
    __shared__ float sb[64];
    __shared__ float w2s[64 * 36];  // W2 [64][32] padded to stride 36 (16B-aligned rows)
    for (int i = threadIdx.x; i < 512; i += 256) w[i] = W1[i];
    if (threadIdx.x < 64) sb[threadIdx.x] = bias[threadIdx.x];
    for (int i = threadIdx.x; i < 2048; i += 256) {
        int r = i >> 5, c = i & 31;
        w2s[r * 36 + c] = W2[i];
    }
    __syncthreads();
    int wid = (blockIdx.x * 256 + threadIdx.x) >> 2;   // node
    if (wid >= n) return;
    int jp = threadIdx.x & 3;          // half2 index (feats 2jp, 2jp+1)
    int start = rs[wid], end = rs[wid + 1];
    float ax = 0.f, ay = 0.f;
    for (int i = start; i < end; i += 16) {
        int idx[16];
        float msk[16];
#pragma unroll
        for (int k = 0; k < 16; ++k) {
            int ii = i + k;
            bool ok = ii < end;
            idx[k] = ok ? csr[ii] : wid;
            msk[k] = ok ? 1.f : 0.f;
        }
        float2 f[16];
#pragma unroll
        for (int k = 0; k < 16; ++k)
            f[k] = __half22float2(hx[((size_t)idx[k] << 2) + jp]);
#pragma unroll
        for (int k = 0; k < 16; ++k) {
            ax = fmaf(msk[k], f[k].x, ax);
            ay = fmaf(msk[k], f[k].y, ay);
        }
    }
    {   // self-loop row
        float2 f = __half22float2(hx[((size_t)wid << 2) + jp]);
        ax += f.x; ay += f.y;
    }
    // quad allgather of aggregated input feats
    float bx = __shfl_xor(ax, 1), by = __shfl_xor(ay, 1);
    float cx = __shfl_xor(ax, 2), cy = __shfl_xor(ay, 2);
    float dx = __shfl_xor(bx, 2), dy = __shfl_xor(by, 2);
    float dv = dinv[wid];
    int fb = jp * 16;   // this lane's g1 slice [fb, fb+16)
    const float* r0 = &w[(2 * jp) * 64 + fb];          const float* r1 = r0 + 64;
    const float* r2 = &w[(2 * (jp ^ 1)) * 64 + fb];    const float* r3 = r2 + 64;
    const float* r4 = &w[(2 * (jp ^ 2)) * 64 + fb];    const float* r5 = r4 + 64;
    const float* r6 = &w[(2 * (jp ^ 3)) * 64 + fb];    const float* r7 = r6 + 64;
    const float* sbp = &sb[fb];
    float4 o4[4];
#pragma unroll
    for (int m4 = 0; m4 < 4; ++m4) {
        float4 wa = *(const float4*)&r0[m4 * 4];
        float4 wb = *(const float4*)&r1[m4 * 4];
        float4 wc = *(const float4*)&r2[m4 * 4];
        float4 wd = *(const float4*)&r3[m4 * 4];
        float4 we = *(const float4*)&r4[m4 * 4];
        float4 wf = *(const float4*)&r5[m4 * 4];
        float4 wg = *(const float4*)&r6[m4 * 4];
        float4 wh = *(const float4*)&r7[m4 * 4];
        float4 o;
        o.x = dv * (ax * wa.x + ay * wb.x + bx * wc.x + by * wd.x + cx * we.x + cy * wf.x + dx * wg.x + dy * wh.x) + sbp[m4 * 4 + 0];
        o.y = dv * (ax * wa.y + ay * wb.y + bx * wc.y + by * wd.y + cx * we.y + cy * wf.y + dx * wg.y + dy * wh.y) + sbp[m4 * 4 + 1];
        o.z = dv * (ax * wa.z + ay * wb.z + bx * wc.z + by * wd.z + cx * we.z + cy * wf.z + dx * wg.z + dy * wh.z) + sbp[m4 * 4 + 2];
        o.w = dv * (ax * wa.w + ay * wb.w + bx * wc.w + by * wd.w + cx * we.w + cy * wf.w + dx * wg.w + dy * wh.w) + sbp[m4 * 4 + 3];
        o.x = o.x > 0.f ? o.x : expm1f(o.x);
        o.y = o.y > 0.f ? o.y : expm1f(o.y);
        o.z = o.z > 0.f ? o.z : expm1f(o.z);
        o.w = o.w > 0.f ? o.w : expm1f(o.w);
        o4[m4] = o;
    }
    // second GEMM: k-rotated per lane (mm = (m4+jp)&3) -> 2-way LDS conflict only
    float4 acc[8];
#pragma unroll
    for (int j4 = 0; j4 < 8; ++j4) acc[j4] = make_float4(0.f, 0.f, 0.f, 0.f);
#pragma unroll
    for (int m4 = 0; m4 < 4; ++m4) {
        int mm = (m4 + jp) & 3;
        float4 ov;
        {
            float4 t0 = (mm & 2) ? o4[2] : o4[0];
            float4 t1 = (mm & 2) ? o4[3] : o4[1];
            ov = (mm & 1) ? t1 : t0;
        }
#pragma unroll
        for (int q = 0; q < 4; ++q) {
            float om = q == 0 ? ov.x : q == 1 ? ov.y : q == 2 ? ov.z : ov.w;
            const float4* wr = (const float4*)&w2s[(fb + mm * 4 + q) * 36];
#pragma unroll
            for (int j4 = 0; j4 < 8; ++j4) {
                float4 wv = wr[j4];
                acc[j4].x = fmaf(om, wv.x, acc[j4].x);
                acc[j4].y = fmaf(om, wv.y, acc[j4].y);
                acc[j4].z = fmaf(om, wv.z, acc[j4].z);
                acc[j4].w = fmaf(om, wv.w, acc[j4].w);
            }
        }
    }
    // butterfly reduce-scatter across the 4 lanes (static indexing only)
    bool hi1 = (jp & 1) != 0;
    float4 keep1[4];
#pragma unroll
    for (int i = 0; i < 4; ++i) {
        float4 lo = acc[i], hi = acc[i + 4];
        float4 mine, send;
        mine.x = hi1 ? hi.x : lo.x;  send.x = hi1 ? lo.x : hi.x;
        mine.y = hi1 ? hi.y : lo.y;  send.y = hi1 ? lo.y : hi.y;
        mine.z = hi1 ? hi.z : lo.z;  send.z = hi1 ? lo.z : hi.z;
        mine.w = hi1 ? hi.w : lo.w;  send.w = hi1 ? lo.w : hi.w;
        mine.x += __shfl_xor(send.x, 1);
        mine.y += __shfl_xor(send.y, 1);
        mine.z += __shfl_xor(send.z, 1);
        mine.w += __shfl_xor(send.w, 1);
        keep1[i] = mine;
    }
    bool hi2 = (jp & 2) != 0;
    float4 fin[2];
#pragma unroll
    for (int i = 0; i < 2; ++i) {
        float4 lo = keep1[i], hi = keep1[i + 2];
        float4 mine, send;
        mine.x = hi2 ? hi.x : lo.x;  send.x = hi2 ? lo.x : hi.x;
        mine.y = hi2 ? hi.y : lo.y;  send.y = hi2 ? lo.y : hi.y;
        mine.z = hi2 ? hi.z : lo.z;  send.z = hi2 ? lo.z : hi.z;
        mine.w = hi2 ? hi.w : lo.w;  send.w = hi2 ? lo.w : hi.w;
        mine.x += __shfl_xor(send.x, 2);
        mine.y += __shfl_xor(send.y, 2);
        mine.z += __shfl_xor(send.z, 2);
        mine.w += __shfl_xor(send.w, 2);
        fin[i] = mine;
    }
    // lane jp holds finished j in [jb, jb+8), jb = (jp&1)*16 + (jp&2)*4
    int jb = (jp & 1) * 16 + (jp & 2) * 4;
    __half2 h01 = __floats2half2_rn(fin[0].x * dv, fin[0].y * dv);
    __half2 h23 = __floats2half2_rn(fin[0].z * dv, fin[0].w * dv);
    __half2 h45 = __floats2half2_rn(fin[1].x * dv, fin[1].y * dv);
    __half2 h67 = __floats2half2_rn(fin[1].z * dv, fin[1].w * dv);
    uint4 u;
    u.x = *(unsigned*)&h01; u.y = *(unsigned*)&h23;
    u.z = *(unsigned*)&h45; u.w = *(unsigned*)&h67;
    *(uint4*)((char*)hw2 + (size_t)wid * 64 + jb * 2) = u;
}

// ---- layer-2: 4 nodes/wave, 16 lanes/node, 16-deep predicated gather ----
__global__ __launch_bounds__(256) void k_aggr32p(const int* __restrict__ rs, const int* __restrict__ csr,
                                                 const float* __restrict__ dinv, const __half* __restrict__ hw,
                                                 const float* __restrict__ bias, float* __restrict__ g, int n) {
    int wid = (blockIdx.x * 256 + threadIdx.x) >> 4;
    if (wid >= n) return;
    int j = threadIdx.x & 15;           // feature pair (feats 2j, 2j+1)
    int start = rs[wid], end = rs[wid + 1];
    const __half2* hp = (const __half2*)hw;
    float ax = 0.f, ay = 0.f;
    for (int i = start; i < end; i += 16) {
        int idx[16];
        float msk[16];
#pragma unroll
        for (int k = 0; k < 16; ++k) {
            int ii = i + k;
            bool ok = ii < end;
            idx[k] = ok ? csr[ii] : wid;
            msk[k] = ok ? 1.f : 0.f;
        }
        float2 f[16];
#pragma unroll
        for (int k = 0; k < 16; ++k)
            f[k] = __half22float2(hp[((size_t)idx[k] << 4) + j]);
#pragma unroll
        for (int k = 0; k < 16; ++k) {
            ax = fmaf(msk[k], f[k].x, ax);
            ay = fmaf(msk[k], f[k].y, ay);
        }
    }
    float dv = dinv[wid];
    float2 fs = __half22float2(hp[((size_t)wid << 4) + j]);
    float2 bb = ((const float2*)bias)[j];
    float vx = dv * (ax + fs.x) + bb.x;
    float vy = dv * (ay + fs.y) + bb.y;
    float2 r;
    r.x = vx > 0.f ? vx : expm1f(vx);
    r.y = vy > 0.f ? vy : expm1f(vy);
    ((float2*)(g + ((size_t)wid << 5)))[j] = r;
}

// ---- cooperative head: conv1d(32->16,k=3)+relu+fc(16->22), 64 rows/block ----
__global__ __launch_bounds__(256) void k_head(const float* __restrict__ g2, const float* __restrict__ cw,
                                              const float* __restrict__ cb, const float* __restrict__ fw,
                                              const float* __restrict__ fb, float* __restrict__ out,
                                              int nrows) {
    __shared__ float tile[(HROWS + 2) * 36];
    __shared__ float scwT[96 * 16];
    __shared__ float ytile[HROWS * 20];
    __shared__ float sfwT[22 * 16];
    __shared__ float scb[16], sfb[22];
    int base = blockIdx.x * HROWS;
    int rcnt = nrows - base; if (rcnt > HROWS) rcnt = HROWS;
    for (int i = threadIdx.x; i < 1536; i += 256) {
        int co = i / 96, rem = i - co * 96;
        scwT[rem * 16 + co] = cw[i];
    }
    for (int i = threadIdx.x; i < 352; i += 256) {
        int co = i / 22, col = i - co * 22;
        sfwT[col * 16 + co] = fw[i];
    }
    if (threadIdx.x < 16) scb[threadIdx.x] = cb[threadIdx.x];
    if (threadIdx.x < 22) sfb[threadIdx.x] = fb[threadIdx.x];
    int nload4 = (rcnt + 2) * 8;
    for (int i = threadIdx.x; i < nload4; i += 256) {
        int r = i >> 3, c4 = i & 7;
        float4 v = *(const float4*)(g2 + (size_t)(base + r) * 32 + c4 * 4);
        *(float4*)&tile[r * 36 + c4 * 4] = v;
    }
    __syncthreads();
    int r = threadIdx.x >> 2;
    int c0 = threadIdx.x & 3;
    if (r < rcnt) {
        float4 acc = { scb[c0 * 4], scb[c0 * 4 + 1], scb[c0 * 4 + 2], scb[c0 * 4 + 3] };
#pragma unroll
        for (int k = 0; k < 3; ++k) {
            const float* tr = &tile[(r + k) * 36];
#pragma unroll
            for (int ci4 = 0; ci4 < 8; ++ci4) {
                float4 xv = *(const float4*)&tr[ci4 * 4];
#pragma unroll
                for (int q = 0; q < 4; ++q) {
                    int ci = ci4 * 4 + q;
                    float4 wv = *(const float4*)&scwT[(ci * 3 + k) * 16 + c0 * 4];
                    float xq = q == 0 ? xv.x : q == 1 ? xv.y : q == 2 ? xv.z : xv.w;
                    acc.x += xq * wv.x;
                    acc.y += xq * wv.y;
                    acc.z += xq * wv.z;
                    acc.w += xq * wv.w;
                }
            }
        }
        float4 yv;
        yv.x = acc.x > 0.f ? acc.x : 0.f;
        yv.y = acc.y > 0.f ? acc.y : 0.f;
        yv.z = acc.z > 0.f ? acc.z : 0.f;
        yv.w = acc.w > 0.f ? acc.w : 0.f;
        *(float4*)&ytile[r * 20 + c0 * 4] = yv;
    }
    __syncthreads();
    int items = rcnt * 22;
    for (int it = threadIdx.x; it < items; it += 256) {
        int row = it / 22, col = it - row * 22;
        const float* yr = &ytile[row * 20];
        const float* wc = &sfwT[col * 16];
        float s = sfb[col];
#pragma unroll
        for (int co4 = 0; co4 < 4; ++co4) {
            float4 yv = *(const float4*)&yr[co4 * 4];
            float4 wv = *(const float4*)&wc[co4 * 4];
            s += yv.x * wv.x + yv.y * wv.y + yv.z * wv.z + yv.w * wv.w;
        }
        out[(size_t)base * 22 + it] = s;
    }
}

extern "C" void kernel_launch(void* const* d_in, const int* in_sizes, int n_in,
                              void* d_out, int out_size, void* d_ws, size_t ws_size,
                              hipStream_t stream) {
    const float* x  = (const float*)d_in[0];
    const int*   ei = (const int*)d_in[1];   // int32 (JAX x64 disabled)
    const float* W1 = (const float*)d_in[2];
    const float* b1 = (const float*)d_in[3];
    const float* W2 = (const float*)d_in[4];
    const float* b2 = (const float*)d_in[5];
    const float* cw = (const float*)d_in[6];
    const float* cb = (const float*)d_in[7];
    const float* fw = (const float*)d_in[8];
    const float* fb = (const float*)d_in[9];
    float* out = (float*)d_out;

    int N = in_sizes[0] / 8;       // 100000
    int E = in_sizes[1] / 2;       // 3200000
    const int* src = ei;
    const int* dst = ei + E;
    int NB = (N + BKT_NODES - 1) >> BKT_SHIFT;  // 391

    auto alignB = [](size_t v) { return (v + 1023) & ~(size_t)1023; };
    char* wsb = (char*)d_ws;
    size_t o = 0;
    int* bcnt = (int*)(wsb + o);      o += 2048;
    int* boff = (int*)(wsb + o);      o += 2048;
    int* bcur = (int*)(wsb + o);      o += 2048;
    int* rowstart = (int*)(wsb + o);  o += alignB((size_t)(N + 1) * 4);
    float* dinv = (float*)(wsb + o);  o += alignB((size_t)N * 4);
    int* csr = (int*)(wsb + o);       o += alignB((size_t)E * 4 + 256);
    __half2* hx = (__half2*)(wsb + o);  o += alignB((size_t)N * 8 * 2);   // [N][8] fp16
    __half* hw2 = (__half*)(wsb + o);   o += alignB((size_t)N * 32 * 2);  // [N][32] fp16
    float* B = (float*)(wsb + o);     o += (size_t)N * 64 * 4;            // g2
    int* ebuf = (int*)B;              // dead before B's first write

    hipMemsetAsync(bcnt, 0, (size_t)NB * sizeof(int), stream);
    k_hist<<<(E + 4095) / 4096, 256, 0, stream>>>(dst, bcnt, E, NB);
    k_bscan<<<1, 512, 0, stream>>>(bcnt, boff, bcur, NB, E);
    k_part<<<(E + 8191) / 8192, 1024, 0, stream>>>(src, dst, bcur, ebuf, E, NB);
    k_lsort<<<NB, 256, 0, stream>>>(boff, ebuf, x, rowstart, dinv, hx, csr, N, NB);

    k_agg1g<<<(int)(((size_t)N * 4 + 255) / 256), 256, 0, stream>>>(rowstart, csr, dinv, hx, W1, b1, W2, hw2, N);

    k_aggr32p<<<(int)(((size_t)N * 16 + 255) / 256), 256, 0, stream>>>(rowstart, csr, dinv, hw2, b2, B, N);

    k_head<<<(N - 2 + HROWS - 1) / HROWS, 256, 0, stream>>>(B, cw, cb, fw, fb, out, N - 2);
}

// Round 23
// 151.027 us; speedup vs baseline: 1.3724x; 1.1393x over previous
//
#include <hip/hip_runtime.h>
#include <hip/hip_fp16.h>
#include <math.h>

#define BKT_SHIFT 8
#define BKT_NODES 256
#define BCAP 9216
#define HROWS 64

// ---- init per-bucket cursors: bcur[b] = b*BCAP ----
__global__ __launch_bounds__(512) void k_init(int* __restrict__ bcur, int NB) {
    int t = blockIdx.x * 512 + threadIdx.x;
    if (t < NB) bcur[t] = t * BCAP;
}

// ---- partition edges into fixed-capacity bucket regions; record = (d&255)<<24 | src ----
__global__ __launch_bounds__(1024) void k_part(const int* __restrict__ src,
                                               const int* __restrict__ dst,
                                               int* __restrict__ bcur,
                                               int* __restrict__ ebuf, int E, int NB) {
    __shared__ int lh[512];
    for (int i = threadIdx.x; i < NB; i += 1024) lh[i] = 0;
    __syncthreads();
    int base = blockIdx.x * 8192;
    if (base + 8192 <= E) {
        const int4* d4 = (const int4*)(dst + base);
#pragma unroll
        for (int k = 0; k < 2; ++k) {
            int4 v = d4[k * 1024 + threadIdx.x];
            atomicAdd(&lh[v.x >> BKT_SHIFT], 1);
            atomicAdd(&lh[v.y >> BKT_SHIFT], 1);
            atomicAdd(&lh[v.z >> BKT_SHIFT], 1);
            atomicAdd(&lh[v.w >> BKT_SHIFT], 1);
        }
    } else {
        for (int k = 0; k < 8; ++k) {
            int i = base + k * 1024 + threadIdx.x;
            if (i < E) atomicAdd(&lh[dst[i] >> BKT_SHIFT], 1);
        }
    }
    __syncthreads();
    for (int t = threadIdx.x; t < NB; t += 1024) {
        int c = lh[t];
        lh[t] = c ? atomicAdd(&bcur[t], c) : 0;
    }
    __syncthreads();
    if (base + 8192 <= E) {
        const int4* d4 = (const int4*)(dst + base);
        const int4* s4 = (const int4*)(src + base);
#pragma unroll
        for (int k = 0; k < 2; ++k) {
            int4 dv = d4[k * 1024 + threadIdx.x];
            int4 sv = s4[k * 1024 + threadIdx.x];
            int p;
            p = atomicAdd(&lh[dv.x >> BKT_SHIFT], 1); ebuf[p] = ((dv.x & 255) << 24) | sv.x;
            p = atomicAdd(&lh[dv.y >> BKT_SHIFT], 1); ebuf[p] = ((dv.y & 255) << 24) | sv.y;
            p = atomicAdd(&lh[dv.z >> BKT_SHIFT], 1); ebuf[p] = ((dv.z & 255) << 24) | sv.z;
            p = atomicAdd(&lh[dv.w >> BKT_SHIFT], 1); ebuf[p] = ((dv.w & 255) << 24) | sv.w;
        }
    } else {
        for (int k = 0; k < 8; ++k) {
            int i = base + k * 1024 + threadIdx.x;
            if (i < E) {
                int d = dst[i];
                int p = atomicAdd(&lh[d >> BKT_SHIFT], 1);
                ebuf[p] = ((d & 255) << 24) | src[i];
            }
        }
    }
}

// ---- counting sort per bucket + rowstart/rowend + dinv + hx (fused) ----
__global__ __launch_bounds__(256) void k_lsort(const int* __restrict__ bcur,
                                               const int* __restrict__ ebuf,
                                               const float* __restrict__ x,
                                               int* __restrict__ rowstart,
                                               int* __restrict__ rowend,
                                               float* __restrict__ dinv,
                                               __half2* __restrict__ hx,
                                               int* __restrict__ csr, int n, int NB) {
    __shared__ int off[256];
    __shared__ int cnt[256];
    int b = blockIdx.x;
    int start = b * BCAP;
    int end = bcur[b];
    cnt[threadIdx.x] = 0;
    __syncthreads();
    for (int i = start + threadIdx.x; i < end; i += 256)
        atomicAdd(&cnt[((unsigned)ebuf[i]) >> 24], 1);
    __syncthreads();
    int v = cnt[threadIdx.x];
    off[threadIdx.x] = v;
    __syncthreads();
    for (int o = 1; o < 256; o <<= 1) {
        int t = (threadIdx.x >= o) ? off[threadIdx.x - o] : 0;
        __syncthreads();
        off[threadIdx.x] += t;
        __syncthreads();
    }
    int excl = off[threadIdx.x] - v;
    int node = (b << BKT_SHIFT) + threadIdx.x;
    if (node < n) {
        rowstart[node] = start + excl;
        rowend[node] = start + excl + v;
        float dv = rsqrtf((float)v + 1.0f);  // +1 = self-loop
        dinv[node] = dv;
        const float4* xp = (const float4*)(x + (size_t)node * 8);
        float4 a = xp[0], c = xp[1];
        __half2* hp = hx + (size_t)node * 4;
        hp[0] = __floats2half2_rn(a.x * dv, a.y * dv);
        hp[1] = __floats2half2_rn(a.z * dv, a.w * dv);
        hp[2] = __floats2half2_rn(c.x * dv, c.y * dv);
        hp[3] = __floats2half2_rn(c.z * dv, c.w * dv);
    }
    __syncthreads();
    off[threadIdx.x] = excl;  // reuse as cursor
    __syncthreads();
    for (int i = start + threadIdx.x; i < end; i += 256) {
        int rec = ebuf[i];
        int d = ((unsigned)rec) >> 24;
        int pos = atomicAdd(&off[d], 1);
        csr[start + pos] = rec & 0xFFFFFF;
    }
}

// ---- fused layer-1 + gemm2: 16 nodes/wave, 4 lanes/node, 16-deep gather,
//      quad-allgather -> g1 (in regs) -> @W2 (k-rotated, conflict-free) -> butterfly -> hw2 ----
__global__ __launch_bounds__(256) void k_agg1g(const int* __restrict__ rs, const int* __restrict__ re,
                                               const int* __restrict__ csr,
                                               const float* __restrict__ dinv, const __half2* __restrict__ hx,
                                               const float* __restrict__ W1, const float* __restrict__ bias,
                                               const float* __restrict__ W2, __half* __restrict__ hw2, int n) {
    __shared__ float w[512];        // W1 [8][64]
    __shared__ float sb[64];
    __shared__ float w2s[64 * 36];  // W2 [64][32] padded to stride 36 (16B-aligned rows)
    for (int i = threadIdx.x; i < 512; i += 256) w[i] = W1[i];
    if (threadIdx.x < 64) sb[threadIdx.x] = bias[threadIdx.x];
    for (int i = threadIdx.x; i < 2048; i += 256) {
        int r = i >> 5, c = i & 31;
        w2s[r * 36 + c] = W2[i];
    }
    __syncthreads();
    int wid = (blockIdx.x * 256 + threadIdx.x) >> 2;   // node
    if (wid >= n) return;
    int jp = threadIdx.x & 3;          // half2 index (feats 2jp, 2jp+1)
    int start = rs[wid], end = re[wid];
    float ax = 0.f, ay = 0.f;
    for (int i = start; i < end; i += 16) {
        int idx[16];
        float msk[16];
#pragma unroll
        for (int k = 0; k < 16; ++k) {
            int ii = i + k;
            bool ok = ii < end;
            idx[k] = ok ? csr[ii] : wid;
            msk[k] = ok ? 1.f : 0.f;
        }
        float2 f[16];
#pragma unroll
        for (int k = 0; k < 16; ++k)
            f[k] = __half22float2(hx[((size_t)idx[k] << 2) + jp]);
#pragma unroll
        for (int k = 0; k < 16; ++k) {
            ax = fmaf(msk[k], f[k].x, ax);
            ay = fmaf(msk[k], f[k].y, ay);
        }
    }
    {   // self-loop row
        float2 f = __half22float2(hx[((size_t)wid << 2) + jp]);
        ax += f.x; ay += f.y;
    }
    // quad allgather of aggregated input feats
    float bx = __shfl_xor(ax, 1), by = __shfl_xor(ay, 1);
    float cx = __shfl_xor(ax, 2), cy = __shfl_xor(ay, 2);
    float dx = __shfl_xor(bx, 2), dy = __shfl_xor(by, 2);
    float dv = dinv[wid];
    int fb = jp * 16;   // this lane's g1 slice [fb, fb+16)
    const float* r0 = &w[(2 * jp) * 64 + fb];          const float* r1 = r0 + 64;
    const float* r2 = &w[(2 * (jp ^ 1)) * 64 + fb];    const float* r3 = r2 + 64;
    const float* r4 = &w[(2 * (jp ^ 2)) * 64 + fb];    const float* r5 = r4 + 64;
    const float* r6 = &w[(2 * (jp ^ 3)) * 64 + fb];    const float* r7 = r6 + 64;
    const float* sbp = &sb[fb];
    float4 o4[4];
#pragma unroll
    for (int m4 = 0; m4 < 4; ++m4) {
        float4 wa = *(const float4*)&r0[m4 * 4];
        float4 wb = *(const float4*)&r1[m4 * 4];
        float4 wc = *(const float4*)&r2[m4 * 4];
        float4 wd = *(const float4*)&r3[m4 * 4];
        float4 we = *(const float4*)&r4[m4 * 4];
        float4 wf = *(const float4*)&r5[m4 * 4];
        float4 wg = *(const float4*)&r6[m4 * 4];
        float4 wh = *(const float4*)&r7[m4 * 4];
        float4 o;
        o.x = dv * (ax * wa.x + ay * wb.x + bx * wc.x + by * wd.x + cx * we.x + cy * wf.x + dx * wg.x + dy * wh.x) + sbp[m4 * 4 + 0];
        o.y = dv * (ax * wa.y + ay * wb.y + bx * wc.y + by * wd.y + cx * we.y + cy * wf.y + dx * wg.y + dy * wh.y) + sbp[m4 * 4 + 1];
        o.z = dv * (ax * wa.z + ay * wb.z + bx * wc.z + by * wd.z + cx * we.z + cy * wf.z + dx * wg.z + dy * wh.z) + sbp[m4 * 4 + 2];
        o.w = dv * (ax * wa.w + ay * wb.w + bx * wc.w + by * wd.w + cx * we.w + cy * wf.w + dx * wg.w + dy * wh.w) + sbp[m4 * 4 + 3];
        o.x = o.x > 0.f ? o.x : expm1f(o.x);
        o.y = o.y > 0.f ? o.y : expm1f(o.y);
        o.z = o.z > 0.f ? o.z : expm1f(o.z);
        o.w = o.w > 0.f ? o.w : expm1f(o.w);
        o4[m4] = o;
    }
    // second GEMM: k-rotated per lane (mm = (m4+jp)&3) -> 2-way LDS conflict only
    float4 acc[8];
#pragma unroll
    for (int j4 = 0; j4 < 8; ++j4) acc[j4] = make_float4(0.f, 0.f, 0.f, 0.f);
#pragma unroll
    for (int m4 = 0; m4 < 4; ++m4) {
        int mm = (m4 + jp) & 3;
        float4 ov;
        {
            float4 t0 = (mm & 2) ? o4[2] : o4[0];
            float4 t1 = (mm & 2) ? o4[3] : o4[1];
            ov = (mm & 1) ? t1 : t0;
        }
#pragma unroll
        for (int q = 0; q < 4; ++q) {
            float om = q == 0 ? ov.x : q == 1 ? ov.y : q == 2 ? ov.z : ov.w;
            const float4* wr = (const float4*)&w2s[(fb + mm * 4 + q) * 36];
#pragma unroll
            for (int j4 = 0; j4 < 8; ++j4) {
                float4 wv = wr[j4];
                acc[j4].x = fmaf(om, wv.x, acc[j4].x);
                acc[j4].y = fmaf(om, wv.y, acc[j4].y);
                acc[j4].z = fmaf(om, wv.z, acc[j4].z);
                acc[j4].w = fmaf(om, wv.w, acc[j4].w);
            }
        }
    }
    // butterfly reduce-scatter across the 4 lanes (static indexing only)
    bool hi1 = (jp & 1) != 0;
    float4 keep1[4];
#pragma unroll
    for (int i = 0; i < 4; ++i) {
        float4 lo = acc[i], hi = acc[i + 4];
        float4 mine, send;
        mine.x = hi1 ? hi.x : lo.x;  send.x = hi1 ? lo.x : hi.x;
        mine.y = hi1 ? hi.y : lo.y;  send.y = hi1 ? lo.y : hi.y;
        mine.z = hi1 ? hi.z : lo.z;  send.z = hi1 ? lo.z : hi.z;
        mine.w = hi1 ? hi.w : lo.w;  send.w = hi1 ? lo.w : hi.w;
        mine.x += __shfl_xor(send.x, 1);
        mine.y += __shfl_xor(send.y, 1);
        mine.z += __shfl_xor(send.z, 1);
        mine.w += __shfl_xor(send.w, 1);
        keep1[i] = mine;
    }
    bool hi2 = (jp & 2) != 0;
    float4 fin[2];
#pragma unroll
    for (int i = 0; i < 2; ++i) {
        float4 lo = keep1[i], hi = keep1[i + 2];
        float4 mine, send;
        mine.x = hi2 ? hi.x : lo.x;  send.x = hi2 ? lo.x : hi.x;
        mine.y = hi2 ? hi.y : lo.y;  send.y = hi2 ? lo.y : hi.y;
        mine.z = hi2 ? hi.z : lo.z;  send.z = hi2 ? lo.z : hi.z;
        mine.w = hi2 ? hi.w : lo.w;  send.w = hi2 ? lo.w : hi.w;
        mine.x += __shfl_xor(send.x, 2);
        mine.y += __shfl_xor(send.y, 2);
        mine.z += __shfl_xor(send.z, 2);
        mine.w += __shfl_xor(send.w, 2);
        fin[i] = mine;
    }
    // lane jp holds finished j in [jb, jb+8), jb = (jp&1)*16 + (jp&2)*4
    int jb = (jp & 1) * 16 + (jp & 2) * 4;
    __half2 h01 = __floats2half2_rn(fin[0].x * dv, fin[0].y * dv);
    __half2 h23 = __floats2half2_rn(fin[0].z * dv, fin[0].w * dv);
    __half2 h45 = __floats2half2_rn(fin[1].x * dv, fin[1].y * dv);
    __half2 h67 = __floats2half2_rn(fin[1].z * dv, fin[1].w * dv);
    uint4 u;
    u.x = *(unsigned*)&h01; u.y = *(unsigned*)&h23;
    u.z = *(unsigned*)&h45; u.w = *(unsigned*)&h67;
    *(uint4*)((char*)hw2 + (size_t)wid * 64 + jb * 2) = u;
}

// ---- layer-2: 4 nodes/wave, 16 lanes/node, 16-deep predicated gather ----
__global__ __launch_bounds__(256) void k_aggr32p(const int* __restrict__ rs, const int* __restrict__ re,
                                                 const int* __restrict__ csr,
                                                 const float* __restrict__ dinv, const __half* __restrict__ hw,
                                                 const float* __restrict__ bias, float* __restrict__ g, int n) {
    int wid = (blockIdx.x * 256 + threadIdx.x) >> 4;
    if (wid >= n) return;
    int j = threadIdx.x & 15;           // feature pair (feats 2j, 2j+1)
    int start = rs[wid], end = re[wid];
    const __half2* hp = (const __half2*)hw;
    float ax = 0.f, ay = 0.f;
    for (int i = start; i < end; i += 16) {
        int idx[16];
        float msk[16];
#pragma unroll
        for (int k = 0; k < 16; ++k) {
            int ii = i + k;
            bool ok = ii < end;
            idx[k] = ok ? csr[ii] : wid;
            msk[k] = ok ? 1.f : 0.f;
        }
        float2 f[16];
#pragma unroll
        for (int k = 0; k < 16; ++k)
            f[k] = __half22float2(hp[((size_t)idx[k] << 4) + j]);
#pragma unroll
        for (int k = 0; k < 16; ++k) {
            ax = fmaf(msk[k], f[k].x, ax);
            ay = fmaf(msk[k], f[k].y, ay);
        }
    }
    float dv = dinv[wid];
    float2 fs = __half22float2(hp[((size_t)wid << 4) + j]);
    float2 bb = ((const float2*)bias)[j];
    float vx = dv * (ax + fs.x) + bb.x;
    float vy = dv * (ay + fs.y) + bb.y;
    float2 r;
    r.x = vx > 0.f ? vx : expm1f(vx);
    r.y = vy > 0.f ? vy : expm1f(vy);
    ((float2*)(g + ((size_t)wid << 5)))[j] = r;
}

// ---- cooperative head: conv1d(32->16,k=3)+relu+fc(16->22), 64 rows/block ----
__global__ __launch_bounds__(256) void k_head(const float* __restrict__ g2, const float* __restrict__ cw,
                                              const float* __restrict__ cb, const float* __restrict__ fw,
                                              const float* __restrict__ fb, float* __restrict__ out,
                                              int nrows) {
    __shared__ float tile[(HROWS + 2) * 36];
    __shared__ float scwT[96 * 16];
    __shared__ float ytile[HROWS * 20];
    __shared__ float sfwT[22 * 16];
    __shared__ float scb[16], sfb[22];
    int base = blockIdx.x * HROWS;
    int rcnt = nrows - base; if (rcnt > HROWS) rcnt = HROWS;
    for (int i = threadIdx.x; i < 1536; i += 256) {
        int co = i / 96, rem = i - co * 96;
        scwT[rem * 16 + co] = cw[i];
    }
    for (int i = threadIdx.x; i < 352; i += 256) {
        int co = i / 22, col = i - co * 22;
        sfwT[col * 16 + co] = fw[i];
    }
    if (threadIdx.x < 16) scb[threadIdx.x] = cb[threadIdx.x];
    if (threadIdx.x < 22) sfb[threadIdx.x] = fb[threadIdx.x];
    int nload4 = (rcnt + 2) * 8;
    for (int i = threadIdx.x; i < nload4; i += 256) {
        int r = i >> 3, c4 = i & 7;
        float4 v = *(const float4*)(g2 + (size_t)(base + r) * 32 + c4 * 4);
        *(float4*)&tile[r * 36 + c4 * 4] = v;
    }
    __syncthreads();
    int r = threadIdx.x >> 2;
    int c0 = threadIdx.x & 3;
    if (r < rcnt) {
        float4 acc = { scb[c0 * 4], scb[c0 * 4 + 1], scb[c0 * 4 + 2], scb[c0 * 4 + 3] };
#pragma unroll
        for (int k = 0; k < 3; ++k) {
            const float* tr = &tile[(r + k) * 36];
#pragma unroll
            for (int ci4 = 0; ci4 < 8; ++ci4) {
                float4 xv = *(const float4*)&tr[ci4 * 4];
#pragma unroll
                for (int q = 0; q < 4; ++q) {
                    int ci = ci4 * 4 + q;
                    float4 wv = *(const float4*)&scwT[(ci * 3 + k) * 16 + c0 * 4];
                    float xq = q == 0 ? xv.x : q == 1 ? xv.y : q == 2 ? xv.z : xv.w;
                    acc.x += xq * wv.x;
                    acc.y += xq * wv.y;
                    acc.z += xq * wv.z;
                    acc.w += xq * wv.w;
                }
            }
        }
        float4 yv;
        yv.x = acc.x > 0.f ? acc.x : 0.f;
        yv.y = acc.y > 0.f ? acc.y : 0.f;
        yv.z = acc.z > 0.f ? acc.z : 0.f;
        yv.w = acc.w > 0.f ? acc.w : 0.f;
        *(float4*)&ytile[r * 20 + c0 * 4] = yv;
    }
    __syncthreads();
    int items = rcnt * 22;
    for (int it = threadIdx.x; it < items; it += 256) {
        int row = it / 22, col = it - row * 22;
        const float* yr = &ytile[row * 20];
        const float* wc = &sfwT[col * 16];
        float s = sfb[col];
#pragma unroll
        for (int co4 = 0; co4 < 4; ++co4) {
            float4 yv = *(const float4*)&yr[co4 * 4];
            float4 wv = *(const float4*)&wc[co4 * 4];
            s += yv.x * wv.x + yv.y * wv.y + yv.z * wv.z + yv.w * wv.w;
        }
        out[(size_t)base * 22 + it] = s;
    }
}

extern "C" void kernel_launch(void* const* d_in, const int* in_sizes, int n_in,
                              void* d_out, int out_size, void* d_ws, size_t ws_size,
                              hipStream_t stream) {
    const float* x  = (const float*)d_in[0];
    const int*   ei = (const int*)d_in[1];   // int32 (JAX x64 disabled)
    const float* W1 = (const float*)d_in[2];
    const float* b1 = (const float*)d_in[3];
    const float* W2 = (const float*)d_in[4];
    const float* b2 = (const float*)d_in[5];
    const float* cw = (const float*)d_in[6];
    const float* cb = (const float*)d_in[7];
    const float* fw = (const float*)d_in[8];
    const float* fb = (const float*)d_in[9];
    float* out = (float*)d_out;

    int N = in_sizes[0] / 8;       // 100000
    int E = in_sizes[1] / 2;       // 3200000
    const int* src = ei;
    const int* dst = ei + E;
    int NB = (N + BKT_NODES - 1) >> BKT_SHIFT;  // 391

    auto alignB = [](size_t v) { return (v + 1023) & ~(size_t)1023; };
    char* wsb = (char*)d_ws;
    size_t o = 0;
    int* bcur = (int*)(wsb + o);      o += 2048;
    int* rowstart = (int*)(wsb + o);  o += alignB((size_t)N * 4);
    int* rowend = (int*)(wsb + o);    o += alignB((size_t)N * 4);
    float* dinv = (float*)(wsb + o);  o += alignB((size_t)N * 4);
    int* csr = (int*)(wsb + o);       o += alignB((size_t)NB * BCAP * 4 + 256);
    __half2* hx = (__half2*)(wsb + o);  o += alignB((size_t)N * 8 * 2);   // [N][8] fp16
    __half* hw2 = (__half*)(wsb + o);   o += alignB((size_t)N * 32 * 2);  // [N][32] fp16
    float* B = (float*)(wsb + o);     o += (size_t)N * 64 * 4;            // g2
    int* ebuf = (int*)B;              // NB*BCAP ints (14.4MB) fits in B (25.6MB); dead before B written

    k_init<<<1, 512, 0, stream>>>(bcur, NB);
    k_part<<<(E + 8191) / 8192, 1024, 0, stream>>>(src, dst, bcur, ebuf, E, NB);
    k_lsort<<<NB, 256, 0, stream>>>(bcur, ebuf, x, rowstart, rowend, dinv, hx, csr, N, NB);

    k_agg1g<<<(int)(((size_t)N * 4 + 255) / 256), 256, 0, stream>>>(rowstart, rowend, csr, dinv, hx, W1, b1, W2, hw2, N);

    k_aggr32p<<<(int)(((size_t)N * 16 + 255) / 256), 256, 0, stream>>>(rowstart, rowend, csr, dinv, hw2, b2, B, N);

    k_head<<<(N - 2 + HROWS - 1) / HROWS, 256, 0, stream>>>(B, cw, cb, fw, fb, out, N - 2);
}